// Round 5
// baseline (593.362 us; speedup 1.0000x reference)
//
#include <hip/hip_runtime.h>
#include <hip/hip_bf16.h>
#include <math.h>

// Problem constants (reference: B=1024, S=200, D=512, O=512)
#define B_  1024
#define S_  200
#define D_  512
#define O_  512

// ---------------------------------------------------------------------------
// setup_kernel: grid 2048 x 64 threads.
//   blocks [0,1024):   Wqk = Wq^T @ Wk  (16x16 tile, BK=32) and, for m-tile 0,
//                      cvec[n] = sum_o Wq_b[o] * Wk[o][n]   (= Wk^T bq)
//   blocks [1024,2048): sqlen[b] = sum(mask[b,:])
// Independent work fused into one dispatch (saves a launch, fills the machine).
// ---------------------------------------------------------------------------
__global__ __launch_bounds__(64) void setup_kernel(
    const float* __restrict__ Wq_w, const float* __restrict__ Wk_w,
    const float* __restrict__ Wq_b, const int* __restrict__ mask,
    float* __restrict__ Wqk, float* __restrict__ cvec, int* __restrict__ sqlen)
{
    const int bid  = blockIdx.x;
    const int lane = threadIdx.x;

    if (bid >= 1024) {                        // ---- sqlen part ----
        const int b = bid - 1024;
        int ssum = 0;
        for (int i = lane; i < S_; i += 64) ssum += mask[b * S_ + i];
#pragma unroll
        for (int off = 32; off; off >>= 1) ssum += __shfl_xor(ssum, off);
        if (lane == 0) sqlen[b] = ssum;
        return;
    }

    // ---- Wqk tile part:  Wqk[m][n] = sum_o Wq[o][m] * Wk[o][n] ----
    constexpr int SA = 20, SB = 20;           // even strides: 8B-aligned float2 reads
    __shared__ float As[32 * SA];
    __shared__ float Bs[32 * SB];
    __shared__ float sBq[32];

    const int m0 = (bid & 31) * 16;
    const int n0 = (bid >> 5) * 16;
    const int ly = lane >> 3, lx = lane & 7;
    const int kr = lane >> 1, c8 = (lane & 1) << 3;

    float a00 = 0.f, a01 = 0.f, a10 = 0.f, a11 = 0.f;
    float cb0 = 0.f, cb1 = 0.f;

    for (int k0 = 0; k0 < O_; k0 += 32) {
        const float* pa = Wq_w + (size_t)(k0 + kr) * D_ + m0 + c8;
        float4 av0 = *(const float4*)pa, av1 = *(const float4*)(pa + 4);
        const float* pb = Wk_w + (size_t)(k0 + kr) * D_ + n0 + c8;
        float4 bv0 = *(const float4*)pb, bv1 = *(const float4*)(pb + 4);
        float bqv = Wq_b[k0 + (lane & 31)];

        __syncthreads();
        *(float4*)&As[kr * SA + c8]     = av0;
        *(float4*)&As[kr * SA + c8 + 4] = av1;
        *(float4*)&Bs[kr * SB + c8]     = bv0;
        *(float4*)&Bs[kr * SB + c8 + 4] = bv1;
        if (lane < 32) sBq[lane] = bqv;
        __syncthreads();

#pragma unroll
        for (int kk = 0; kk < 32; ++kk) {
            float2 a = *(const float2*)&As[kk * SA + (ly << 1)];
            float2 b = *(const float2*)&Bs[kk * SB + (lx << 1)];
            a00 = fmaf(a.x, b.x, a00); a01 = fmaf(a.x, b.y, a01);
            a10 = fmaf(a.y, b.x, a10); a11 = fmaf(a.y, b.y, a11);
            float qv = sBq[kk];
            cb0 = fmaf(qv, b.x, cb0); cb1 = fmaf(qv, b.y, cb1);
        }
    }

    const int r0 = m0 + (ly << 1);
    const int c0 = n0 + (lx << 1);
    *(float2*)(Wqk + (size_t)r0 * D_ + c0)       = make_float2(a00, a01);
    *(float2*)(Wqk + (size_t)(r0 + 1) * D_ + c0) = make_float2(a10, a11);
    if ((bid & 31) == 0 && ly == 0)
        *(float2*)(cvec + c0) = make_float2(cb0, cb1);
}

// ---------------------------------------------------------------------------
// gemm32x16: fp32 GEMM, 32x16 output tile per 1-wave block, BK=32.
// Two M-halves per lane -> inner loop 8 FMA : 3 ds_read_b64 (2x density of a
// 16x16 tile). Grid (M/32, N/16) = 1024 blocks -> 4 blocks/CU.
//   GATHER: A-row m is x[m, sq[m]-1, :] (lda = row stride of x's s-dim)
//   BMODE 1: B is [K][N] row-major;  BMODE 0: B is [N][K] row-major (use B^T)
//   TANH:   C = tanh(C + bias)  else C = C + bias
// ---------------------------------------------------------------------------
template<bool GATHER, int BMODE, bool TANH>
__global__ __launch_bounds__(64) void gemm32x16(
    const float* __restrict__ A, const float* __restrict__ Bm,
    const float* __restrict__ bias, float* __restrict__ C,
    const int* __restrict__ sq, int N, int K, int lda, int ldb)
{
    constexpr int SA = 34;                       // even: aligned float2, conflict-free
    constexpr int SB = (BMODE == 0) ? 18 : 20;
    __shared__ float As[32 * SA];
    __shared__ float Bs[32 * SB];

    const int lane = threadIdx.x;
    const int m0 = blockIdx.x * 32;
    const int n0 = blockIdx.y * 16;
    const int ly = lane >> 3, lx = lane & 7;

    // A staging: lane covers row ar, k-halves akc..akc+15
    const int ar  = lane >> 1;                   // 0..31
    const int akc = (lane & 1) << 4;             // 0 or 16
    const float* arow;
    if (GATHER) {
        const int b = m0 + ar;
        arow = A + ((size_t)b * S_ + (sq[b] - 1)) * (size_t)lda + akc;
    } else {
        arow = A + (size_t)(m0 + ar) * lda + akc;
    }

    float l00 = 0.f, l01 = 0.f, l10 = 0.f, l11 = 0.f;
    float h00 = 0.f, h01 = 0.f, h10 = 0.f, h11 = 0.f;

    for (int k0 = 0; k0 < K; k0 += 32) {
        float4 a0 = *(const float4*)(arow + k0);
        float4 a1 = *(const float4*)(arow + k0 + 4);
        float4 a2 = *(const float4*)(arow + k0 + 8);
        float4 a3 = *(const float4*)(arow + k0 + 12);
        float4 b0, b1;
        if (BMODE == 1) {
            const float* pb = Bm + (size_t)(k0 + (lane >> 1)) * ldb + n0 + ((lane & 1) << 3);
            b0 = *(const float4*)pb; b1 = *(const float4*)(pb + 4);
        } else {
            const float* pb = Bm + (size_t)(n0 + (lane >> 2)) * ldb + k0 + ((lane & 3) << 3);
            b0 = *(const float4*)pb; b1 = *(const float4*)(pb + 4);
        }

        __syncthreads();   // prior iteration's LDS reads done (1 wave: cheap)

        {   // scatter-transpose A into As[k][m]
            const float av[16] = {a0.x,a0.y,a0.z,a0.w, a1.x,a1.y,a1.z,a1.w,
                                  a2.x,a2.y,a2.z,a2.w, a3.x,a3.y,a3.z,a3.w};
#pragma unroll
            for (int j = 0; j < 16; ++j) As[(akc + j) * SA + ar] = av[j];
        }
        if (BMODE == 1) {
            const int kr = lane >> 1, nc = (lane & 1) << 3;
            *(float4*)&Bs[kr * SB + nc]     = b0;
            *(float4*)&Bs[kr * SB + nc + 4] = b1;
        } else {
            const int nr = lane >> 2, kc = (lane & 3) << 3;
            Bs[(kc + 0) * SB + nr] = b0.x; Bs[(kc + 1) * SB + nr] = b0.y;
            Bs[(kc + 2) * SB + nr] = b0.z; Bs[(kc + 3) * SB + nr] = b0.w;
            Bs[(kc + 4) * SB + nr] = b1.x; Bs[(kc + 5) * SB + nr] = b1.y;
            Bs[(kc + 6) * SB + nr] = b1.z; Bs[(kc + 7) * SB + nr] = b1.w;
        }
        __syncthreads();

#pragma unroll
        for (int kk = 0; kk < 32; ++kk) {
            float2 al = *(const float2*)&As[kk * SA + (ly << 1)];
            float2 ah = *(const float2*)&As[kk * SA + 16 + (ly << 1)];
            float2 b  = *(const float2*)&Bs[kk * SB + (lx << 1)];
            l00 = fmaf(al.x, b.x, l00); l01 = fmaf(al.x, b.y, l01);
            l10 = fmaf(al.y, b.x, l10); l11 = fmaf(al.y, b.y, l11);
            h00 = fmaf(ah.x, b.x, h00); h01 = fmaf(ah.x, b.y, h01);
            h10 = fmaf(ah.y, b.x, h10); h11 = fmaf(ah.y, b.y, h11);
        }
    }

    const int c0 = n0 + (lx << 1);
    const float bb0 = bias[c0], bb1 = bias[c0 + 1];
    float o0 = l00 + bb0, o1 = l01 + bb1, o2 = l10 + bb0, o3 = l11 + bb1;
    float o4 = h00 + bb0, o5 = h01 + bb1, o6 = h10 + bb0, o7 = h11 + bb1;
    if (TANH) {
        o0 = tanhf(o0); o1 = tanhf(o1); o2 = tanhf(o2); o3 = tanhf(o3);
        o4 = tanhf(o4); o5 = tanhf(o5); o6 = tanhf(o6); o7 = tanhf(o7);
    }
    const int rl = m0 + (ly << 1);
    const int rh = rl + 16;
    *(float2*)(C + (size_t)rl * N + c0)       = make_float2(o0, o1);
    *(float2*)(C + (size_t)(rl + 1) * N + c0) = make_float2(o2, o3);
    *(float2*)(C + (size_t)rh * N + c0)       = make_float2(o4, o5);
    *(float2*)(C + (size_t)(rh + 1) * N + c0) = make_float2(o6, o7);
}

// ---------------------------------------------------------------------------
// attn: fused masked attention over x directly.
//   scores[s] = x[b,s,:] . qk[b,:]      (q.bk dropped: softmax shift-invariant)
//   ctx[b,:]  = sum_s softmax(scores)[s] * x[b,s,:]
// One block per b, 4 waves; wave w owns row quads {4w..4w+3} + 16t.
// 4 rows/iter: 4 interleaved shuffle chains (ILP), 2x fewer serial online-
// softmax steps. Next quad prefetched (clamped). 4 wave states merged in LDS.
// ---------------------------------------------------------------------------
__global__ __launch_bounds__(256) void attn_kernel(
    const float* __restrict__ x, const float* __restrict__ qk,
    const int* __restrict__ sqlen, float* __restrict__ ctx)
{
    const int b    = blockIdx.x;
    const int tid  = threadIdx.x;
    const int w    = tid >> 6;
    const int lane = tid & 63;
    const int L    = sqlen[b] - 1;           // #valid keys, >= 1

    const float* qkb = qk + (size_t)b * D_ + lane * 8;
    const float4 q0 = *(const float4*)qkb;
    const float4 q1 = *(const float4*)(qkb + 4);

    float m = -INFINITY, l = 0.f;
    float acc[8] = {0.f, 0.f, 0.f, 0.f, 0.f, 0.f, 0.f, 0.f};

    int s0 = w * 4;
    if (s0 < L) {
        const float* base = x + (size_t)b * S_ * D_ + lane * 8;
        const int i1 = (s0 + 1 < L) ? s0 + 1 : L - 1;
        const int i2 = (s0 + 2 < L) ? s0 + 2 : L - 1;
        const int i3 = (s0 + 3 < L) ? s0 + 3 : L - 1;
        float4 c0 = *(const float4*)(base + (size_t)s0 * D_);
        float4 c1 = *(const float4*)(base + (size_t)s0 * D_ + 4);
        float4 c2 = *(const float4*)(base + (size_t)i1 * D_);
        float4 c3 = *(const float4*)(base + (size_t)i1 * D_ + 4);
        float4 c4 = *(const float4*)(base + (size_t)i2 * D_);
        float4 c5 = *(const float4*)(base + (size_t)i2 * D_ + 4);
        float4 c6 = *(const float4*)(base + (size_t)i3 * D_);
        float4 c7 = *(const float4*)(base + (size_t)i3 * D_ + 4);
        for (;;) {
            const int  sn   = s0 + 16;
            const bool more = sn < L;
            const int  j0 = more ? sn : s0;
            const int  j1 = more ? ((sn + 1 < L) ? sn + 1 : L - 1) : s0;
            const int  j2 = more ? ((sn + 2 < L) ? sn + 2 : L - 1) : s0;
            const int  j3 = more ? ((sn + 3 < L) ? sn + 3 : L - 1) : s0;
            float4 n0 = *(const float4*)(base + (size_t)j0 * D_);
            float4 n1 = *(const float4*)(base + (size_t)j0 * D_ + 4);
            float4 n2 = *(const float4*)(base + (size_t)j1 * D_);
            float4 n3 = *(const float4*)(base + (size_t)j1 * D_ + 4);
            float4 n4 = *(const float4*)(base + (size_t)j2 * D_);
            float4 n5 = *(const float4*)(base + (size_t)j2 * D_ + 4);
            float4 n6 = *(const float4*)(base + (size_t)j3 * D_);
            float4 n7 = *(const float4*)(base + (size_t)j3 * D_ + 4);

            float p0 = c0.x*q0.x + c0.y*q0.y + c0.z*q0.z + c0.w*q0.w
                     + c1.x*q1.x + c1.y*q1.y + c1.z*q1.z + c1.w*q1.w;
            float p1 = c2.x*q0.x + c2.y*q0.y + c2.z*q0.z + c2.w*q0.w
                     + c3.x*q1.x + c3.y*q1.y + c3.z*q1.z + c3.w*q1.w;
            float p2 = c4.x*q0.x + c4.y*q0.y + c4.z*q0.z + c4.w*q0.w
                     + c5.x*q1.x + c5.y*q1.y + c5.z*q1.z + c5.w*q1.w;
            float p3 = c6.x*q0.x + c6.y*q0.y + c6.z*q0.z + c6.w*q0.w
                     + c7.x*q1.x + c7.y*q1.y + c7.z*q1.z + c7.w*q1.w;
#pragma unroll
            for (int off = 32; off; off >>= 1) {
                p0 += __shfl_xor(p0, off);
                p1 += __shfl_xor(p1, off);
                p2 += __shfl_xor(p2, off);
                p3 += __shfl_xor(p3, off);
            }
            if (s0 + 1 >= L) p1 = -INFINITY;
            if (s0 + 2 >= L) p2 = -INFINITY;
            if (s0 + 3 >= L) p3 = -INFINITY;

            const float mn = fmaxf(fmaxf(m, fmaxf(p0, p1)), fmaxf(p2, p3));
            const float r  = __expf(m  - mn);   // m=-inf first iter -> 0
            const float e0 = __expf(p0 - mn);
            const float e1 = __expf(p1 - mn);
            const float e2 = __expf(p2 - mn);
            const float e3 = __expf(p3 - mn);
            l = l * r + e0 + e1 + e2 + e3;
            acc[0] = acc[0]*r + e0*c0.x + e1*c2.x + e2*c4.x + e3*c6.x;
            acc[1] = acc[1]*r + e0*c0.y + e1*c2.y + e2*c4.y + e3*c6.y;
            acc[2] = acc[2]*r + e0*c0.z + e1*c2.z + e2*c4.z + e3*c6.z;
            acc[3] = acc[3]*r + e0*c0.w + e1*c2.w + e2*c4.w + e3*c6.w;
            acc[4] = acc[4]*r + e0*c1.x + e1*c3.x + e2*c5.x + e3*c7.x;
            acc[5] = acc[5]*r + e0*c1.y + e1*c3.y + e2*c5.y + e3*c7.y;
            acc[6] = acc[6]*r + e0*c1.z + e1*c3.z + e2*c5.z + e3*c7.z;
            acc[7] = acc[7]*r + e0*c1.w + e1*c3.w + e2*c5.w + e3*c7.w;
            m = mn;

            if (!more) break;
            s0 = sn;
            c0 = n0; c1 = n1; c2 = n2; c3 = n3;
            c4 = n4; c5 = n5; c6 = n6; c7 = n7;
        }
    }

    // merge 4 per-wave online-softmax states (flash-style combine)
    __shared__ float s_m[4], s_l[4];
    __shared__ float s_ctx[4][D_];
    if (lane == 0) { s_m[w] = m; s_l[w] = l; }
#pragma unroll
    for (int j = 0; j < 8; ++j) s_ctx[w][lane * 8 + j] = acc[j];
    __syncthreads();

    const float M4 = fmaxf(fmaxf(s_m[0], s_m[1]), fmaxf(s_m[2], s_m[3]));
    const float sc0 = __expf(s_m[0] - M4);   // empty wave: -inf -> 0
    const float sc1 = __expf(s_m[1] - M4);
    const float sc2 = __expf(s_m[2] - M4);
    const float sc3 = __expf(s_m[3] - M4);
    const float lt  = s_l[0]*sc0 + s_l[1]*sc1 + s_l[2]*sc2 + s_l[3]*sc3;
    const float inv = 1.f / lt;

    const int d = tid * 2;
    float v0 = (s_ctx[0][d]     * sc0 + s_ctx[1][d]     * sc1 +
                s_ctx[2][d]     * sc2 + s_ctx[3][d]     * sc3) * inv;
    float v1 = (s_ctx[0][d + 1] * sc0 + s_ctx[1][d + 1] * sc1 +
                s_ctx[2][d + 1] * sc2 + s_ctx[3][d + 1] * sc3) * inv;
    *(float2*)(ctx + (size_t)b * D_ + d) = make_float2(v0, v1);
}

// ---------------------------------------------------------------------------
// Orchestration (4 dispatches).
//   qk[b] = Wk^T(Wq xlast_b + bq) = Wqk^T xlast_b + c,  Wqk = Wq^T Wk,
//   c = Wk^T bq; K-bias dropped (softmax shift-invariance); V folded after
//   attention: out = tanh(Wv ctx + bv) since sum(attn)=1.
// ws: sqlen int[1024] | cvec f32[512] | Wqk f32[512x512] | qk | ctx  (~5 MB)
// ---------------------------------------------------------------------------
extern "C" void kernel_launch(void* const* d_in, const int* in_sizes, int n_in,
                              void* d_out, int out_size, void* d_ws, size_t ws_size,
                              hipStream_t stream)
{
    const float* x    = (const float*)d_in[0];
    const int*   mask = (const int*)  d_in[1];
    const float* Wq_w = (const float*)d_in[2];
    const float* Wq_b = (const float*)d_in[3];
    const float* Wk_w = (const float*)d_in[4];
    const float* Wk_b = (const float*)d_in[5];   // unused: softmax shift invariance
    const float* Wv_w = (const float*)d_in[6];
    const float* Wv_b = (const float*)d_in[7];
    (void)Wk_b; (void)in_sizes; (void)n_in; (void)out_size; (void)ws_size;
    float* out = (float*)d_out;

    char* ws = (char*)d_ws;
    int*   sqlen = (int*)ws;                                   // 4 KB
    float* cvec  = (float*)(ws + 4096);                        // 4 KB slot
    float* Wqk   = (float*)(ws + 8192);                        // 1 MB
    float* qk    = (float*)(ws + 8192 + (1u << 20));           // 2 MB
    float* ctxb  = qk + (size_t)B_ * D_;                       // 2 MB

    // Wqk = Wq^T Wk, cvec = Wk^T bq, sqlen = rowsum(mask)  (fused dispatch)
    setup_kernel<<<2048, 64, 0, stream>>>(Wq_w, Wk_w, Wq_b, mask, Wqk, cvec, sqlen);

    // qk = x[b, sqlen[b]-1, :] @ Wqk + cvec   (gather folded into GEMM)
    gemm32x16<true, 1, false><<<dim3(B_ / 32, D_ / 16), 64, 0, stream>>>(
        x, Wqk, cvec, qk, sqlen, D_, D_, D_, D_);

    // fused masked softmax-attention over x -> ctx
    attn_kernel<<<B_, 256, 0, stream>>>(x, qk, sqlen, ctxb);

    // out = tanh(ctx @ Wv^T + bv)
    gemm32x16<false, 0, true><<<dim3(B_ / 32, O_ / 16), 64, 0, stream>>>(
        ctxb, Wv_w, Wv_b, out, nullptr, O_, D_, D_, D_);
}